// Round 1
// baseline (28.535 us; speedup 1.0000x reference)
//
#include <hip/hip_runtime.h>
#include <math.h>

// Van Rossum loss:
//   f[t] = r*f[t-1] + c*x[t],  x = spike - target, r = exp(dt/tau), c = exp(-(T-1)dt/tau)/tau
//   loss = mean_b sum_{t,n} f[b,t,n]^2
// Chunked linear-scan decomposition over T so we get enough parallelism:
//   per chunk (len L, zero-init local scan l[k]):
//     E = l[L-1], B = sum_k r^{k+1} l[k], C = sum_k l[k]^2
//   sum over chunk of f^2 = A*F^2 + 2*F*B + C,  A = sum_k r^{2(k+1)} (const)
//   F <- r^L * F + E   (F = carried full-scan state, F_{-1} = 0)

#define B_DIM 32
#define T_DIM 1024
#define N_DIM 256
#define NCHUNK 32
#define LCHUNK 32              // T_DIM / NCHUNK
#define NQ 64                  // N_DIM / 4 (float4 per thread)
#define SERIES_Q (B_DIM * NQ)  // 2048

__global__ __launch_bounds__(256) void vr_pass1(
    const float* __restrict__ spike, const float* __restrict__ target,
    float4* __restrict__ wsE, float4* __restrict__ wsB,
    float* __restrict__ out,
    float r, float cp, float invB)
{
    int g = blockIdx.x * 256 + threadIdx.x;   // ((b*NCHUNK + chunk) * NQ) + q
    int q     = g & (NQ - 1);
    int bc    = g >> 6;
    int chunk = bc & (NCHUNK - 1);
    int b     = bc >> 5;
    int t0    = chunk * LCHUNK;

    size_t base = ((size_t)(b * T_DIM + t0) * N_DIM) + ((size_t)q << 2);
    const float4* sp = reinterpret_cast<const float4*>(spike + base);
    const float4* tg = reinterpret_cast<const float4*>(target + base);

    float4 l  = make_float4(0.f, 0.f, 0.f, 0.f);
    float4 Bs = make_float4(0.f, 0.f, 0.f, 0.f);
    float4 Cs = make_float4(0.f, 0.f, 0.f, 0.f);
    float w = r;
    #pragma unroll 8
    for (int k = 0; k < LCHUNK; ++k) {
        float4 s = sp[k * (N_DIM / 4)];
        float4 t = tg[k * (N_DIM / 4)];
        float xx = s.x - t.x, xy = s.y - t.y, xz = s.z - t.z, xw = s.w - t.w;
        l.x = fmaf(r, l.x, cp * xx);
        l.y = fmaf(r, l.y, cp * xy);
        l.z = fmaf(r, l.z, cp * xz);
        l.w = fmaf(r, l.w, cp * xw);
        Bs.x = fmaf(w, l.x, Bs.x);
        Bs.y = fmaf(w, l.y, Bs.y);
        Bs.z = fmaf(w, l.z, Bs.z);
        Bs.w = fmaf(w, l.w, Bs.w);
        Cs.x = fmaf(l.x, l.x, Cs.x);
        Cs.y = fmaf(l.y, l.y, Cs.y);
        Cs.z = fmaf(l.z, l.z, Cs.z);
        Cs.w = fmaf(l.w, l.w, Cs.w);
        w *= r;
    }
    int o = (chunk * B_DIM + b) * NQ + q;
    wsE[o] = l;
    wsB[o] = Bs;

    // C contributes directly (independent of carried state): block-reduce + 1 atomic
    float c = (Cs.x + Cs.y) + (Cs.z + Cs.w);
    #pragma unroll
    for (int off = 32; off > 0; off >>= 1) c += __shfl_down(c, off);
    __shared__ float red[4];
    int lane = threadIdx.x & 63, wid = threadIdx.x >> 6;
    if (lane == 0) red[wid] = c;
    __syncthreads();
    if (threadIdx.x == 0)
        atomicAdd(out, ((red[0] + red[1]) + (red[2] + red[3])) * invB);
}

__global__ __launch_bounds__(64) void vr_pass2(
    const float4* __restrict__ wsE, const float4* __restrict__ wsB,
    float* __restrict__ out, float rL, float A, float invB)
{
    int g = blockIdx.x * 64 + threadIdx.x;    // b*NQ + q, g < 2048
    int q = g & (NQ - 1);
    int b = g >> 6;

    float4 F = make_float4(0.f, 0.f, 0.f, 0.f);
    float acc = 0.f;
    #pragma unroll 4
    for (int chunk = 0; chunk < NCHUNK; ++chunk) {
        int o = (chunk * B_DIM + b) * NQ + q;
        float4 E  = wsE[o];
        float4 Bv = wsB[o];
        acc += A * ((F.x * F.x + F.y * F.y) + (F.z * F.z + F.w * F.w))
             + 2.f * ((F.x * Bv.x + F.y * Bv.y) + (F.z * Bv.z + F.w * Bv.w));
        F.x = fmaf(rL, F.x, E.x);
        F.y = fmaf(rL, F.y, E.y);
        F.z = fmaf(rL, F.z, E.z);
        F.w = fmaf(rL, F.w, E.w);
    }
    acc *= invB;
    #pragma unroll
    for (int off = 32; off > 0; off >>= 1) acc += __shfl_down(acc, off);
    if ((threadIdx.x & 63) == 0) atomicAdd(out, acc);
}

extern "C" void kernel_launch(void* const* d_in, const int* in_sizes, int n_in,
                              void* d_out, int out_size, void* d_ws, size_t ws_size,
                              hipStream_t stream)
{
    (void)in_sizes; (void)n_in; (void)ws_size;
    const float* spike  = (const float*)d_in[0];
    const float* target = (const float*)d_in[1];
    float* out = (float*)d_out;

    float4* wsE = (float4*)d_ws;
    float4* wsB = wsE + (size_t)NCHUNK * B_DIM * NQ;   // 2 x 1 MiB

    const double tau = 20.0, dt = 1.0;
    const double rd = exp(dt / tau);
    const double r2 = rd * rd;
    const float r    = (float)rd;
    const float cp   = (float)(exp(-(double)(T_DIM - 1) * dt / tau) / tau);
    const float rL   = (float)exp((double)LCHUNK * dt / tau);
    const float A    = (float)(r2 * (pow(r2, (double)LCHUNK) - 1.0) / (r2 - 1.0));
    const float invB = 1.0f / (float)B_DIM;

    hipMemsetAsync(d_out, 0, sizeof(float) * out_size, stream);
    hipLaunchKernelGGL(vr_pass1, dim3((B_DIM * NCHUNK * NQ) / 256), dim3(256), 0, stream,
                       spike, target, wsE, wsB, out, r, cp, invB);
    hipLaunchKernelGGL(vr_pass2, dim3(SERIES_Q / 64), dim3(64), 0, stream,
                       wsE, wsB, out, rL, A, invB);
}